// Round 15
// baseline (307.856 us; speedup 1.0000x reference)
//
#include <hip/hip_runtime.h>
#include <hip/hip_bf16.h>
#include <stdint.h>

// MultiHeadAttention: B=32, NQ=T=1024, E=128, H=8, dk=dv=16
// Inputs FLOAT32, output FLOAT32. Internal bf16 MFMA.
// S^T via mfma_f32_32x32x16_bf16 (K=16==dk). PV ALSO via 32x32x16 with ones
// stacked into V rows 16-31 -> one MFMA chain yields O^T AND the softmax
// denominator. P transforms C-layout -> B-layout IN REGISTERS (shfl_xor 32),
// no LDS round-trip. exp2-domain softmax, no max shift (constant cancels).
// LUT AND-masking. attn: 32 q/wave, 1 wave/block.
// 3 launches: projqkv+maskpack -> flash-attn -> out-proj.

typedef __attribute__((ext_vector_type(8))) short bf16x8;    // MFMA A/B frag
typedef __attribute__((ext_vector_type(4))) float f32x4;     // 16x16 C/D frag
typedef __attribute__((ext_vector_type(16))) float f32x16;   // 32x32 C/D frag

#define QSCALE 0.36067376022224085f   // (1/sqrt(16)) * log2(e)
#define EXP2(x) __builtin_amdgcn_exp2f(x)   // raw v_exp_f32 (2^x)

__device__ __forceinline__ unsigned short f2bf(float x) {
  union { __hip_bfloat16 h; unsigned short u; } cv;
  cv.h = __float2bfloat16(x);
  return cv.u;
}
// pack two f32 -> two bf16 (round-half-up): low=a, high=b
__device__ __forceinline__ unsigned int pk2bf(float a, float b) {
  unsigned int ua = __float_as_uint(a) + 0x8000u;
  unsigned int ub = __float_as_uint(b) + 0x8000u;
  return __builtin_amdgcn_perm(ub, ua, 0x07060302u);
}
// pack two f32 -> two bf16 (truncate; 1 instr): low=a, high=b
__device__ __forceinline__ unsigned int pk2bf_t(float a, float b) {
  return __builtin_amdgcn_perm(__float_as_uint(b), __float_as_uint(a), 0x07060302u);
}

// ---------------- fused Q/K/V projection + mask packing (one grid) ----------------
// blocks 0..1535: sel = x>>9 -> Q / K / V^T projection (64-row tile each)
// blocks 1536..9727: mask pack (16 elems/thread -> bit per (b,q,t))
__global__ __launch_bounds__(256) void projmask_k(const float* __restrict__ qp,
                                                  const float* __restrict__ hp,
                                                  const float* __restrict__ wqp,
                                                  const float* __restrict__ wkp,
                                                  const float* __restrict__ wvp,
                                                  const void* __restrict__ mask,
                                                  unsigned short* __restrict__ Qb,
                                                  unsigned short* __restrict__ Kb,
                                                  unsigned short* __restrict__ Vt,
                                                  unsigned long long* __restrict__ mp64) {
  __shared__ unsigned short WtLds[128 * 136];
  __shared__ __align__(16) unsigned short Cxf[9216];
  const int tid = threadIdx.x;

  if (blockIdx.x >= 1536) {   // ---------- mask-pack blocks ----------
    const int bx = blockIdx.x - 1536;
    unsigned short* mlds = WtLds;  // reuse LDS
    const unsigned int* mi = (const unsigned int*)mask;
    unsigned int accv = 0;
    #pragma unroll
    for (int k = 0; k < 16; ++k) accv |= mi[k * 251];
    const bool bytemode = accv > 1u;

    const long long i0 = ((long long)bx * 256 + tid) * 16;
    unsigned int v = 0;
    if (bytemode) {
      int4 w = *(const int4*)((const unsigned char*)mask + i0);
      unsigned int ws[4] = {(unsigned)w.x, (unsigned)w.y, (unsigned)w.z, (unsigned)w.w};
      #pragma unroll
      for (int d = 0; d < 4; ++d)
        #pragma unroll
        for (int j = 0; j < 4; ++j)
          v |= (((ws[d] >> (8*j)) & 0xFFu) ? 1u : 0u) << (d*4 + j);
    } else {
      const int4* mp4 = (const int4*)((const int*)mask + i0);
      #pragma unroll
      for (int d = 0; d < 4; ++d) {
        int4 w = mp4[d];
        v |= (w.x ? 1u : 0u) << (d*4 + 0);
        v |= (w.y ? 1u : 0u) << (d*4 + 1);
        v |= (w.z ? 1u : 0u) << (d*4 + 2);
        v |= (w.w ? 1u : 0u) << (d*4 + 3);
      }
    }
    mlds[tid] = (unsigned short)v;
    __syncthreads();
    if (tid < 64)
      mp64[(long long)bx * 64 + tid] = ((const unsigned long long*)mlds)[tid];
    return;
  }

  // ---------- projection blocks ----------
  const int wave = tid >> 6, lane = tid & 63;
  const int llo4 = lane & 15, lhi4 = lane >> 4;
  const int xb = blockIdx.x & 511;
  const int sel = blockIdx.x >> 9;
  const int m0 = xb * 64;
  const int b = m0 >> 10, row0 = m0 & 1023;
  const float* A = (sel == 0) ? qp : hp;
  const float* W = (sel == 0) ? wqp : (sel == 1) ? wkp : wvp;
  const float wscale = (sel == 0) ? QSCALE : 1.0f;

  #pragma unroll
  for (int i = 0; i < 8; ++i) {
    int base = (tid + i * 256) * 8;
    float4 w0 = *(const float4*)&W[base];
    float4 w1 = *(const float4*)&W[base + 4];
    float wv8[8] = {w0.x, w0.y, w0.z, w0.w, w1.x, w1.y, w1.z, w1.w};
    #pragma unroll
    for (int j = 0; j < 8; ++j) {
      int idx = base + j;
      int h = idx >> 11, e = (idx >> 4) & 127, kk = idx & 15;
      WtLds[(h*16 + kk) * 136 + e] = f2bf(wv8[j] * wscale);
    }
  }
  #pragma unroll
  for (int i = 0; i < 4; ++i) {
    int r = (tid >> 4) + i * 16;
    int c = (tid & 15) * 8;
    float4 a0 = *(const float4*)&A[(m0 + r) * 128 + c];
    float4 a1 = *(const float4*)&A[(m0 + r) * 128 + c + 4];
    bf16x8 a8;
    a8[0] = (short)f2bf(a0.x); a8[1] = (short)f2bf(a0.y);
    a8[2] = (short)f2bf(a0.z); a8[3] = (short)f2bf(a0.w);
    a8[4] = (short)f2bf(a1.x); a8[5] = (short)f2bf(a1.y);
    a8[6] = (short)f2bf(a1.z); a8[7] = (short)f2bf(a1.w);
    *(bf16x8*)&Cxf[r * 136 + c] = a8;
  }
  __syncthreads();

  const int n0 = wave * 32;
  f32x4 acc[4][2] = {};
  #pragma unroll
  for (int kk = 0; kk < 128; kk += 32) {
    bf16x8 af[4], bfr[2];
    #pragma unroll
    for (int mi2 = 0; mi2 < 4; ++mi2)
      af[mi2] = *(const bf16x8*)&Cxf[(mi2*16 + llo4)*136 + kk + lhi4*8];
    #pragma unroll
    for (int ni = 0; ni < 2; ++ni)
      bfr[ni] = *(const bf16x8*)&WtLds[(n0 + ni*16 + llo4)*136 + kk + lhi4*8];
    #pragma unroll
    for (int mi2 = 0; mi2 < 4; ++mi2)
      #pragma unroll
      for (int ni = 0; ni < 2; ++ni)
        acc[mi2][ni] = __builtin_amdgcn_mfma_f32_16x16x32_bf16(af[mi2], bfr[ni], acc[mi2][ni], 0, 0, 0);
  }

  __syncthreads();
  if (sel < 2) {
    unsigned short* Cb = sel ? Kb : Qb;
    #pragma unroll
    for (int mi2 = 0; mi2 < 4; ++mi2)
      #pragma unroll
      for (int ni = 0; ni < 2; ++ni) {
        int n = n0 + ni*16 + llo4;
        #pragma unroll
        for (int r = 0; r < 4; ++r)
          Cxf[(mi2*16 + lhi4*4 + r)*136 + n] = f2bf(acc[mi2][ni][r]);
      }
    __syncthreads();
    #pragma unroll
    for (int it = 0; it < 4; ++it) {
      int u = tid + it*256;
      int h = u >> 7, rk = u & 127, row = rk >> 1, kh = rk & 1;
      bf16x8 vv = *(const bf16x8*)&Cxf[row*136 + h*16 + kh*8];
      *(bf16x8*)&Cb[((b*8 + h)*1024 + row0 + row)*16 + kh*8] = vv;
    }
  } else {
    #pragma unroll
    for (int mi2 = 0; mi2 < 4; ++mi2)
      #pragma unroll
      for (int ni = 0; ni < 2; ++ni) {
        int n = n0 + ni*16 + llo4;
        ushort4 pk;
        pk.x = f2bf(acc[mi2][ni][0]); pk.y = f2bf(acc[mi2][ni][1]);
        pk.z = f2bf(acc[mi2][ni][2]); pk.w = f2bf(acc[mi2][ni][3]);
        *(ushort4*)&Cxf[n*72 + mi2*16 + lhi4*4] = pk;
      }
    __syncthreads();
    #pragma unroll
    for (int it = 0; it < 4; ++it) {
      int u = tid + it*256;
      int n = u >> 3, tc = u & 7;
      int h = n >> 4, k = n & 15;
      bf16x8 vv = *(const bf16x8*)&Cxf[n*72 + tc*8];
      *(bf16x8*)&Vt[((b*8 + h)*16 + k)*1024 + row0 + tc*8] = vv;
    }
  }
}

// ---------------- flash attention (1 wave/block, all-32x32, register P-exchange) ----
// grid (NQ/32, B, H); the single wave owns queries x*32 .. +31 of head z.
// S^T: C/D col q=lane&31, row t=(r&3)+8*(r>>2)+4*(lane>>5).
// PV: A = [V^T rows 0..15 ; ones rows 16..31], B = P^T (n=q=lane&31,
// k=t=(lane>>5)*8+j) built from S regs via one shfl_xor(32) pair per sub-tile.
// acc rows 0..15 = O^T, rows 16..31 = denominator (in-lane at acc[8]).
__global__ __launch_bounds__(64) void attn_k(const unsigned short* __restrict__ Qb,
                                             const unsigned short* __restrict__ Kb,
                                             const unsigned short* __restrict__ Vtb,
                                             const unsigned long long* __restrict__ mp64,
                                             unsigned short* __restrict__ heads) {
  __shared__ __align__(8) uint2 mlut[16];  // nibble -> 4 halfword AND-masks
  const int lane = threadIdx.x;
  const int llo5 = lane & 31, lhi5 = lane >> 5;
  const int q0 = blockIdx.x * 32;
  const int b  = blockIdx.y;
  const int h  = blockIdx.z;
  const int bh = b * 8 + h;
  const unsigned long long* mp_base = &mp64[((b << 10) + q0 + llo5) * 16];
  const unsigned short* Kbase = &Kb[(bh * 1024 + llo5) * 16 + lhi5 * 8];
  const unsigned short* Vbase = &Vtb[(bh * 16 + (llo5 & 15)) * 1024 + lhi5 * 8];

  if (lane < 16) {
    unsigned int n = lane;
    unsigned int h0 = (n & 1u) ? 0u : 0xFFFFu;
    unsigned int h1 = (n & 2u) ? 0u : 0xFFFFu;
    unsigned int h2 = (n & 4u) ? 0u : 0xFFFFu;
    unsigned int h3 = (n & 8u) ? 0u : 0xFFFFu;
    mlut[lane] = make_uint2(h0 | (h1 << 16), h2 | (h3 << 16));
  }
  // single wave: LDS write->read ordering via lgkmcnt, no barrier needed

  // Q^T B-frag (32 q wide, k = lhi5*8+j covers full dk=16)
  bf16x8 qf = *(const bf16x8*)&Qb[(bh * 1024 + q0 + llo5) * 16 + lhi5 * 8];

  bf16x8 ones8;
  #pragma unroll
  for (int j = 0; j < 8; ++j) ones8[j] = (short)0x3F80;  // bf16 1.0
  const f32x16 z16 = {};

  f32x16 acc = {};   // col q=llo5; rows 0-15: O^T(v), rows 16-31: denom

  // 2-phase K/mask pipeline; V loaded per-iteration (consumed late)
  bf16x8 kfb[2][2];
  unsigned long long mwb[2];

  #pragma unroll
  for (int tt = 0; tt < 2; ++tt)
    kfb[0][tt] = *(const bf16x8*)&Kbase[(tt*32) * 16];
  mwb[0] = mp_base[0];

  #pragma unroll 2
  for (int tw = 0; tw < 16; ++tw) {
    const int cur = tw & 1, nxt = cur ^ 1;
    const int twn = (tw < 15) ? tw + 1 : 15;
    const int t0  = tw * 64;
    // prefetch next K tile + mask word
    #pragma unroll
    for (int tt = 0; tt < 2; ++tt)
      kfb[nxt][tt] = *(const bf16x8*)&Kbase[(twn*64 + tt*32) * 16];
    mwb[nxt] = mp_base[twn];

    // current tile's stacked-V A-frags: rows 0-15 = V^T, rows 16-31 = 1.0
    bf16x8 vs[4];
    #pragma unroll
    for (int s = 0; s < 4; ++s) {
      vs[s] = ones8;
      if (llo5 < 16)
        vs[s] = *(const bf16x8*)&Vbase[t0 + s*16];
    }

    // S^T = K*Q^T : two 32x32x16 MFMAs, then exp2 in place (no max shift;
    // the constant factor cancels in O = (P V)/(P 1))
    f32x16 st[2];
    #pragma unroll
    for (int tt = 0; tt < 2; ++tt) {
      st[tt] = __builtin_amdgcn_mfma_f32_32x32x16_bf16(kfb[cur][tt], qf, z16, 0, 0, 0);
      #pragma unroll
      for (int r = 0; r < 16; ++r)
        st[tt][r] = EXP2(st[tt][r]);
    }

    // per 16-t sub-tile: pack+mask 4 uints, exchange across lane^32, MFMA
    const unsigned int mwlo = (unsigned int)mwb[cur];
    const unsigned int mwhi = (unsigned int)(mwb[cur] >> 32);
    #pragma unroll
    for (int s = 0; s < 4; ++s) {
      const int tt = s >> 1, rb = (s & 1) * 8;
      const unsigned int m32 = (tt ? mwhi : mwlo) >> (lhi5 * 4);
      const int g0 = (s & 1) * 2;
      uint2 amA = mlut[(m32 >> (g0*8)) & 0xFu];
      uint2 amB = mlut[(m32 >> (g0*8 + 8)) & 0xFu];
      unsigned int A = pk2bf_t(st[tt][rb+0], st[tt][rb+1]) & amA.x;
      unsigned int Bq = pk2bf_t(st[tt][rb+2], st[tt][rb+3]) & amA.y;
      unsigned int C = pk2bf_t(st[tt][rb+4], st[tt][rb+5]) & amB.x;
      unsigned int D = pk2bf_t(st[tt][rb+6], st[tt][rb+7]) & amB.y;
      unsigned int Y1 = __shfl_xor(lhi5 ? A : C, 32);
      unsigned int Y2 = __shfl_xor(lhi5 ? Bq : D, 32);
      union { unsigned int u[4]; bf16x8 v; } pf;
      pf.u[0] = lhi5 ? Y1 : A;
      pf.u[1] = lhi5 ? Y2 : Bq;
      pf.u[2] = lhi5 ? C  : Y1;
      pf.u[3] = lhi5 ? D  : Y2;
      acc = __builtin_amdgcn_mfma_f32_32x32x16_bf16(vs[s], pf.v, acc, 0, 0, 0);
    }
  }

  // rows 16-31 all equal the denominator; every lane holds one at reg 8
  float l = acc[8];
  float inv = l > 0.f ? 1.f / l : 0.f;
  // O^T: reg r (0..7) -> v = (r&3) + 8*(r>>2) + 4*lhi5, q = q0 + llo5
  unsigned short* hp2 = &heads[((b << 10) + q0 + llo5) * 128 + h*16];
  uint2 d0, d1;
  d0.x = pk2bf(acc[0]*inv, acc[1]*inv);
  d0.y = pk2bf(acc[2]*inv, acc[3]*inv);
  d1.x = pk2bf(acc[4]*inv, acc[5]*inv);
  d1.y = pk2bf(acc[6]*inv, acc[7]*inv);
  *(uint2*)&hp2[4*lhi5]     = d0;   // v = 4*lhi5 .. +3
  *(uint2*)&hp2[8 + 4*lhi5] = d1;   // v = 8 + 4*lhi5 .. +3
}

// ---------------- output projection ----------------
__global__ __launch_bounds__(256) void outproj_k(const unsigned short* __restrict__ Av,
                                                 const float* __restrict__ W,
                                                 float* __restrict__ Co) {
  __shared__ unsigned short WtLds[128 * 136];
  __shared__ __align__(16) unsigned short Cxf[9216];
  const int tid = threadIdx.x;
  const int wave = tid >> 6, lane = tid & 63;
  const int llo4 = lane & 15, lhi4 = lane >> 4;
  const int m0 = blockIdx.x * 64;

  #pragma unroll
  for (int i = 0; i < 8; ++i) {
    int base = (tid + i * 256) * 8;
    float4 w0 = *(const float4*)&W[base];
    float4 w1 = *(const float4*)&W[base + 4];
    float wv8[8] = {w0.x, w0.y, w0.z, w0.w, w1.x, w1.y, w1.z, w1.w};
    #pragma unroll
    for (int j = 0; j < 8; ++j) {
      int idx = base + j;
      WtLds[(idx & 127) * 136 + (idx >> 7)] = f2bf(wv8[j]);
    }
  }
  #pragma unroll
  for (int i = 0; i < 4; ++i) {
    int r = (tid >> 4) + i * 16;
    int c = (tid & 15) * 8;
    *(bf16x8*)&Cxf[r * 136 + c] = *(const bf16x8*)&Av[(m0 + r) * 128 + c];
  }
  __syncthreads();

  const int n0 = wave * 32;
  f32x4 acc[4][2] = {};
  #pragma unroll
  for (int kk = 0; kk < 128; kk += 32) {
    bf16x8 af[4], bfr[2];
    #pragma unroll
    for (int mi2 = 0; mi2 < 4; ++mi2)
      af[mi2] = *(const bf16x8*)&Cxf[(mi2*16 + llo4)*136 + kk + lhi4*8];
    #pragma unroll
    for (int ni = 0; ni < 2; ++ni)
      bfr[ni] = *(const bf16x8*)&WtLds[(n0 + ni*16 + llo4)*136 + kk + lhi4*8];
    #pragma unroll
    for (int mi2 = 0; mi2 < 4; ++mi2)
      #pragma unroll
      for (int ni = 0; ni < 2; ++ni)
        acc[mi2][ni] = __builtin_amdgcn_mfma_f32_16x16x32_bf16(af[mi2], bfr[ni], acc[mi2][ni], 0, 0, 0);
  }
  #pragma unroll
  for (int mi2 = 0; mi2 < 4; ++mi2)
    #pragma unroll
    for (int ni = 0; ni < 2; ++ni) {
      int n = n0 + ni*16 + llo4;
      int mbase = m0 + mi2*16 + lhi4*4;
      #pragma unroll
      for (int r = 0; r < 4; ++r)
        Co[(mbase + r) * 128 + n] = acc[mi2][ni][r];
    }
}

extern "C" void kernel_launch(void* const* d_in, const int* in_sizes, int n_in,
                              void* d_out, int out_size, void* d_ws, size_t ws_size,
                              hipStream_t stream) {
  const float* q  = (const float*)d_in[0];
  const float* hh = (const float*)d_in[1];
  const void*  mk = d_in[2];
  const float* wq = (const float*)d_in[3];
  const float* wk = (const float*)d_in[4];
  const float* wv = (const float*)d_in[5];
  const float* wo = (const float*)d_in[6];
  float* out = (float*)d_out;

  unsigned short* Qb = (unsigned short*)d_ws;       // [B][H][NQ][16]  8.4 MB
  unsigned short* Kb = Qb + 32*8*1024*16;           // [B][H][T][16]   8.4 MB
  unsigned short* Vt = Kb + 32*8*1024*16;           // [B][H][16][T]   8.4 MB
  unsigned short* hd = Vt + 32*8*1024*16;           // [B*NQ][128]     8.4 MB
  unsigned long long* mp64 = (unsigned long long*)(hd + 32768*128); // 4.2 MB

  projmask_k<<<9728, 256, 0, stream>>>(q, hh, wq, wk, wv, mk, Qb, Kb, Vt, mp64);
  attn_k<<<dim3(32, 32, 8), 64, 0, stream>>>(Qb, Kb, Vt, mp64, hd);
  outproj_k<<<512, 256, 0, stream>>>(hd, wo, out);
}